// Round 19
// baseline (360.208 us; speedup 1.0000x reference)
//
#include <hip/hip_runtime.h>
#include <cstdint>
#include <cstddef>

// ---------------------------------------------------------------------------
// RelativeTransformerEncoderLayer on MI355X (gfx950)
// T=2048 B=2 D=1024 NH=8 DH=64 DFF=4096
// ---------------------------------------------------------------------------

typedef unsigned short ushort_t;
typedef __bf16 bf16x8 __attribute__((ext_vector_type(8)));
typedef float f32x4 __attribute__((ext_vector_type(4)));
typedef unsigned short us8 __attribute__((ext_vector_type(8)));
typedef unsigned short us4 __attribute__((ext_vector_type(4)));

#define DEV static __device__ __forceinline__

DEV ushort_t f2bf(float x) {
  union { float f; unsigned u; } v; v.f = x;
  unsigned r = (v.u + 0x7FFFu + ((v.u >> 16) & 1u)) >> 16;
  return (ushort_t)r;
}
DEV ushort_t f2bt(float x) {              // truncating (internal use)
  union { float f; unsigned u; } v; v.f = x;
  return (ushort_t)(v.u >> 16);
}
DEV float bf2f(ushort_t h) {
  union { unsigned u; float f; } v; v.u = ((unsigned)h) << 16;
  return v.f;
}
DEV float fexp2(float x) { float r; asm("v_exp_f32 %0, %1" : "=v"(r) : "v"(x)); return r; }
DEV f32x4 mfma16(bf16x8 a, bf16x8 b, f32x4 c) {
  return __builtin_amdgcn_mfma_f32_16x16x32_bf16(a, b, c, 0, 0, 0);
}
// async global->LDS, 16B per lane; dest = wave-uniform base + lane*16 (linear).
DEV void gld16(const void* g, void* l) {
  __builtin_amdgcn_global_load_lds((const __attribute__((address_space(1))) void*)g,
                                   (__attribute__((address_space(3))) void*)l,
                                   16, 0, 0);
}

constexpr float SCLQ = 0.125f * 1.44269504088896f;   // 1/sqrt(64) * log2(e)

// ---------------- workspace layout (bytes) ----------------
constexpr size_t O_QKV_F  = 0;
constexpr size_t O_QKV_B  = 3145728;
constexpr size_t O_RNET_F = 6291456;
constexpr size_t O_RNET_B = 7340032;
constexpr size_t O_WO     = 8388608;
constexpr size_t O_W1     = 10485760;
constexpr size_t O_W2     = 18874368;
constexpr size_t O_RKREV_F= 27262976;
constexpr size_t O_RKREV_B= 29360128;
constexpr size_t O_QAC_F  = 31457280;
constexpr size_t O_QBD_F  = 35651584;
constexpr size_t O_KK_F   = 39845888;
constexpr size_t O_VT_F   = 44040192;
constexpr size_t O_QAC_B  = 48234496;
constexpr size_t O_QBD_B  = 52428800;
constexpr size_t O_KK_B   = 56623104;
constexpr size_t O_VT_B   = 60817408;
constexpr size_t O_H      = 65011712;
constexpr size_t O_LN3    = 81788928;
constexpr size_t ZONE     = 90177536;
constexpr size_t O_POS    = ZONE + 0;
constexpr size_t O_LN1    = ZONE + 4194304;
constexpr size_t O_LN2    = ZONE + 12582912;
constexpr size_t O_HEADS_F= ZONE + 20971520;   // unused (v fused); kept for layout
constexpr size_t O_HEADS_B= ZONE + 33554432;
constexpr size_t O_ACAT   = ZONE + 0;
constexpr size_t O_FFNM   = ZONE + 8388608;
// ffn2 split-K bf16 partials: overlay dead attention operand region (8MB each)
constexpr size_t O_FPART  = O_QAC_F;

// --------------------- merged prep: cvt (8 segs) + ln_dual -------------------
struct PrepArgs {
  const float* src[8];
  ushort_t* dst[8];
  int bstart[8];
  int cvt_blocks;
  const float* x;
  const float* g1; const float* b1;
  const float* g2; const float* b2;
  ushort_t* o1; ushort_t* o2;
};
__global__ __launch_bounds__(256)
void prep_k(PrepArgs a) {
  __shared__ float sbuf[8];
  const int bx = blockIdx.x;
  const int tid = threadIdx.x;
  if (bx < a.cvt_blocks) {
    int s = 0;
#pragma unroll
    for (int k = 1; k < 8; ++k) if (bx >= a.bstart[k]) s = k;
    int i = (bx - a.bstart[s]) * 256 + tid;
    float4 v = reinterpret_cast<const float4*>(a.src[s])[i];
    us4 o; o[0] = f2bf(v.x); o[1] = f2bf(v.y); o[2] = f2bf(v.z); o[3] = f2bf(v.w);
    reinterpret_cast<us4*>(a.dst[s])[i] = o;
    return;
  }
  const int row = bx - a.cvt_blocks;
  const float* xr = a.x + (size_t)row * 1024;
  float4 v = reinterpret_cast<const float4*>(xr)[tid];
  float s  = v.x + v.y + v.z + v.w;
  float s2 = v.x*v.x + v.y*v.y + v.z*v.z + v.w*v.w;
  for (int m = 32; m >= 1; m >>= 1) { s += __shfl_xor(s, m, 64); s2 += __shfl_xor(s2, m, 64); }
  int w = tid >> 6;
  if ((tid & 63) == 0) { sbuf[w] = s; sbuf[4 + w] = s2; }
  __syncthreads();
  float S  = sbuf[0] + sbuf[1] + sbuf[2] + sbuf[3];
  float S2 = sbuf[4] + sbuf[5] + sbuf[6] + sbuf[7];
  float mu  = S * (1.f / 1024.f);
  float var = S2 * (1.f / 1024.f) - mu * mu;
  float inv = rsqrtf(var + 1e-5f);
  int t = row >> 1, b = row & 1;
  size_t r2 = ((size_t)(2047 - t) * 2 + b) * 1024;
  float4 G1 = reinterpret_cast<const float4*>(a.g1)[tid];
  float4 B1 = reinterpret_cast<const float4*>(a.b1)[tid];
  float4 G2 = reinterpret_cast<const float4*>(a.g2)[tid];
  float4 B2 = reinterpret_cast<const float4*>(a.b2)[tid];
  float n0 = (v.x - mu) * inv, n1 = (v.y - mu) * inv, n2 = (v.z - mu) * inv, n3 = (v.w - mu) * inv;
  us4 aa, c;
  aa[0] = f2bf(n0 * G1.x + B1.x); aa[1] = f2bf(n1 * G1.y + B1.y);
  aa[2] = f2bf(n2 * G1.z + B1.z); aa[3] = f2bf(n3 * G1.w + B1.w);
  c[0] = f2bf(n0 * G2.x + B2.x); c[1] = f2bf(n1 * G2.y + B2.y);
  c[2] = f2bf(n2 * G2.z + B2.z); c[3] = f2bf(n3 * G2.w + B2.w);
  reinterpret_cast<us4*>(a.o1 + (size_t)row * 1024)[tid] = aa;
  reinterpret_cast<us4*>(a.o2 + r2)[tid] = c;
}

// -------------------------- LayerNorm (single) ------------------------------
__global__ __launch_bounds__(256)
void ln_one_k(const float* __restrict__ x,
              const float* __restrict__ g1, const float* __restrict__ b1,
              ushort_t* __restrict__ o1) {
  __shared__ float sbuf[8];
  const int row = blockIdx.x;
  const int tid = threadIdx.x;
  const float* xr = x + (size_t)row * 1024;
  float4 v = reinterpret_cast<const float4*>(xr)[tid];
  float s  = v.x + v.y + v.z + v.w;
  float s2 = v.x*v.x + v.y*v.y + v.z*v.z + v.w*v.w;
  for (int m = 32; m >= 1; m >>= 1) { s += __shfl_xor(s, m, 64); s2 += __shfl_xor(s2, m, 64); }
  int w = tid >> 6;
  if ((tid & 63) == 0) { sbuf[w] = s; sbuf[4 + w] = s2; }
  __syncthreads();
  float S  = sbuf[0] + sbuf[1] + sbuf[2] + sbuf[3];
  float S2 = sbuf[4] + sbuf[5] + sbuf[6] + sbuf[7];
  float mu  = S * (1.f / 1024.f);
  float var = S2 * (1.f / 1024.f) - mu * mu;
  float inv = rsqrtf(var + 1e-5f);
  float4 G1 = reinterpret_cast<const float4*>(g1)[tid];
  float4 B1 = reinterpret_cast<const float4*>(b1)[tid];
  us4 a;
  a[0] = f2bf((v.x - mu) * inv * G1.x + B1.x);
  a[1] = f2bf((v.y - mu) * inv * G1.y + B1.y);
  a[2] = f2bf((v.z - mu) * inv * G1.z + B1.z);
  a[3] = f2bf((v.w - mu) * inv * G1.w + B1.w);
  reinterpret_cast<us4*>(o1 + (size_t)row * 1024)[tid] = a;
}

// ------------------------------ GEMM 128x128 --------------------------------
template <int EPI>
__global__ __launch_bounds__(256)
void gemm_bt(const ushort_t* __restrict__ A, const ushort_t* __restrict__ B,
             void* __restrict__ C, const float* __restrict__ bias,
             const float* __restrict__ resid, int M, int N, int K) {
  __shared__ ushort_t As[128 * 64];
  __shared__ ushort_t Bs[128 * 64];
  const int tid = threadIdx.x;
  const int lane = tid & 63;
  const int w = tid >> 6;
  const int wm = w >> 1, wn = w & 1;
  const int row0 = blockIdx.y * 128, col0 = blockIdx.x * 128;
  const int lr = lane & 15;
  const int lkb = (lane >> 4) * 8;
  const int rr = lane >> 3;
  const int scb = ((lane & 7) ^ rr) * 8;
  const f32x4 fz = {0.f, 0.f, 0.f, 0.f};
  f32x4 acc[4][4];
#pragma unroll
  for (int i = 0; i < 4; ++i)
#pragma unroll
    for (int j = 0; j < 4; ++j) acc[i][j] = fz;

  for (int k0 = 0; k0 < K; k0 += 64) {
    __syncthreads();
#pragma unroll
    for (int it = 0; it < 4; ++it) {
      int rbase = it * 32 + w * 8;
      gld16(A + (size_t)(row0 + rbase + rr) * K + k0 + scb, (char*)As + rbase * 128);
      gld16(B + (size_t)(col0 + rbase + rr) * K + k0 + scb, (char*)Bs + rbase * 128);
    }
    __syncthreads();
#pragma unroll
    for (int kk = 0; kk < 64; kk += 32) {
      bf16x8 af[4], bfr[4];
#pragma unroll
      for (int mi = 0; mi < 4; ++mi) {
        int r = wm * 64 + mi * 16 + lr;
        int off = (r * 128 + (kk + lkb) * 2) ^ ((r & 7) << 4);
        af[mi] = *reinterpret_cast<const bf16x8*>((char*)As + off);
      }
#pragma unroll
      for (int ni = 0; ni < 4; ++ni) {
        int r = wn * 64 + ni * 16 + lr;
        int off = (r * 128 + (kk + lkb) * 2) ^ ((r & 7) << 4);
        bfr[ni] = *reinterpret_cast<const bf16x8*>((char*)Bs + off);
      }
#pragma unroll
      for (int mi = 0; mi < 4; ++mi)
#pragma unroll
        for (int ni = 0; ni < 4; ++ni)
          acc[mi][ni] = mfma16(af[mi], bfr[ni], acc[mi][ni]);
    }
  }
#pragma unroll
  for (int mi = 0; mi < 4; ++mi)
#pragma unroll
    for (int ni = 0; ni < 4; ++ni)
#pragma unroll
      for (int r = 0; r < 4; ++r) {
        int row = row0 + wm * 64 + mi * 16 + (lane >> 4) * 4 + r;
        int col = col0 + wn * 64 + ni * 16 + lr;
        float v = acc[mi][ni][r];
        if (EPI == 0) {
          ((ushort_t*)C)[(size_t)row * N + col] = f2bf(v);
        } else if (EPI == 1) {
          v += bias[col]; v = v > 0.f ? v : 0.f;
          ((ushort_t*)C)[(size_t)row * N + col] = f2bf(v);
        } else {
          v += bias[col] + resid[(size_t)row * N + col];
          ((float*)C)[(size_t)row * N + col] = v;
        }
      }
}

// ----------------- merged QKV (fused post, v->vt direct) + rk ----------------
// Flat 1D grid of 896 active blocks: id<768 -> qkv (z=id/384; 12x32 tiles);
// id>=768 -> rk (z=2+(id-768)/64; 4x16 tiles). V writes go straight to the
// [bn][dh][t] vt layout (v_trans kernel eliminated).
__global__ __launch_bounds__(256)
void qkvrk_k(const ushort_t* __restrict__ A0, const ushort_t* __restrict__ A1,
             const ushort_t* __restrict__ A2,
             const ushort_t* __restrict__ B0, const ushort_t* __restrict__ B1,
             const ushort_t* __restrict__ B2, const ushort_t* __restrict__ B3,
             char* __restrict__ wsb,
             const float* __restrict__ rw0, const float* __restrict__ rr0,
             const float* __restrict__ rw1, const float* __restrict__ rr1) {
  const int id = (int)blockIdx.x;
  int z, bxx, byy;
  if (id < 768) {
    z = id / 384;
    int rem = id - z * 384;
    bxx = rem % 12;
    byy = rem / 12;
  } else {
    int id2 = id - 768;
    z = 2 + (id2 >> 6);
    int rem = id2 & 63;
    bxx = rem & 3;
    byy = rem >> 2;
  }
  const ushort_t* A = (z == 0) ? A0 : (z == 1) ? A1 : A2;
  const ushort_t* B = (z == 0) ? B0 : (z == 1) ? B1 : (z == 2) ? B2 : B3;

  __shared__ ushort_t As[128 * 64];
  __shared__ ushort_t Bs[128 * 64];
  const int tid = threadIdx.x;
  const int lane = tid & 63;
  const int w = tid >> 6;
  const int wm = w >> 1, wn = w & 1;
  const int row0 = byy * 128, col0 = bxx * 128;
  const int lr = lane & 15;
  const int lkb = (lane >> 4) * 8;
  const int rr = lane >> 3;
  const int scb = ((lane & 7) ^ rr) * 8;
  const f32x4 fz = {0.f, 0.f, 0.f, 0.f};
  f32x4 acc[4][4];
#pragma unroll
  for (int i = 0; i < 4; ++i)
#pragma unroll
    for (int j = 0; j < 4; ++j) acc[i][j] = fz;

  for (int k0 = 0; k0 < 1024; k0 += 64) {
    __syncthreads();
#pragma unroll
    for (int it = 0; it < 4; ++it) {
      int rbase = it * 32 + w * 8;
      gld16(A + (size_t)(row0 + rbase + rr) * 1024 + k0 + scb, (char*)As + rbase * 128);
      gld16(B + (size_t)(col0 + rbase + rr) * 1024 + k0 + scb, (char*)Bs + rbase * 128);
    }
    __syncthreads();
#pragma unroll
    for (int kk = 0; kk < 64; kk += 32) {
      bf16x8 af[4], bfr[4];
#pragma unroll
      for (int mi = 0; mi < 4; ++mi) {
        int r = wm * 64 + mi * 16 + lr;
        int off = (r * 128 + (kk + lkb) * 2) ^ ((r & 7) << 4);
        af[mi] = *reinterpret_cast<const bf16x8*>((char*)As + off);
      }
#pragma unroll
      for (int ni = 0; ni < 4; ++ni) {
        int r = wn * 64 + ni * 16 + lr;
        int off = (r * 128 + (kk + lkb) * 2) ^ ((r & 7) << 4);
        bfr[ni] = *reinterpret_cast<const bf16x8*>((char*)Bs + off);
      }
#pragma unroll
      for (int mi = 0; mi < 4; ++mi)
#pragma unroll
        for (int ni = 0; ni < 4; ++ni)
          acc[mi][ni] = mfma16(af[mi], bfr[ni], acc[mi][ni]);
    }
  }
  const int dirz = z & 1;
  const float* rwb = dirz ? rw1 : rw0;
  const float* rrb = dirz ? rr1 : rr0;
#pragma unroll
  for (int mi = 0; mi < 4; ++mi)
#pragma unroll
    for (int ni = 0; ni < 4; ++ni)
#pragma unroll
      for (int r = 0; r < 4; ++r) {
        int row = row0 + wm * 64 + mi * 16 + (lane >> 4) * 4 + r;
        int col = col0 + wn * 64 + ni * 16 + lr;
        float v = acc[mi][ni][r];
        if (z < 2) {        // qkv fused post-process
          int t = row >> 1, bb = row & 1;
          if (col < 512) {
            int nn = col >> 6, dh = col & 63;
            ushort_t* q_ac = (ushort_t*)(wsb + (dirz ? O_QAC_B : O_QAC_F));
            ushort_t* q_bd = (ushort_t*)(wsb + (dirz ? O_QBD_B : O_QBD_F));
            size_t o = ((size_t)(bb * 8 + nn) * 2048 + t) * 64 + dh;
            q_ac[o] = f2bf((v + rwb[col]) * SCLQ);
            q_bd[o] = f2bf((v + rrb[col]) * SCLQ);
          } else if (col < 1024) {
            int cc = col - 512;
            int nn = cc >> 6, dh = cc & 63;
            ushort_t* kout = (ushort_t*)(wsb + (dirz ? O_KK_B : O_KK_F));
            kout[((size_t)(bb * 8 + nn) * 2048 + t) * 64 + dh] = f2bf(v);
          } else {          // v -> vt [bn][dh][t] directly
            int cc = col - 1024;
            int nn = cc >> 6, dh = cc & 63;
            ushort_t* vt = (ushort_t*)(wsb + (dirz ? O_VT_B : O_VT_F));
            vt[((size_t)(bb * 8 + nn) * 64 + dh) * 2048 + t] = f2bf(v);
          }
        } else {            // rk fused reverse
          ushort_t* rkrev = (ushort_t*)(wsb + (dirz ? O_RKREV_B : O_RKREV_F));
          int nn = col >> 6, dh = col & 63;
          rkrev[((size_t)nn * 2048 + (2047 - row)) * 64 + dh] = f2bf(v);
        }
      }
}

// ------------------------- GEMM 128x128, z-dispatch --------------------------
// EPI 5: bf16 partial store (split-K). lda/ldb row strides (elements).
template <int EPI>
__global__ __launch_bounds__(256)
void gemm_bt2(const ushort_t* __restrict__ A0, const ushort_t* __restrict__ A1,
              const ushort_t* __restrict__ B0, const ushort_t* __restrict__ B1,
              void* __restrict__ C0, void* __restrict__ C1,
              int M, int N, int K, int lda, int ldb) {
  __shared__ ushort_t As[128 * 64];
  __shared__ ushort_t Bs[128 * 64];
  const ushort_t* A = blockIdx.z ? A1 : A0;
  const ushort_t* B = blockIdx.z ? B1 : B0;
  void* C = blockIdx.z ? (void*)C1 : (void*)C0;
  const int tid = threadIdx.x;
  const int lane = tid & 63;
  const int w = tid >> 6;
  const int wm = w >> 1, wn = w & 1;
  const int row0 = blockIdx.y * 128, col0 = blockIdx.x * 128;
  const int lr = lane & 15;
  const int lkb = (lane >> 4) * 8;
  const int rr = lane >> 3;
  const int scb = ((lane & 7) ^ rr) * 8;
  const f32x4 fz = {0.f, 0.f, 0.f, 0.f};
  f32x4 acc[4][4];
#pragma unroll
  for (int i = 0; i < 4; ++i)
#pragma unroll
    for (int j = 0; j < 4; ++j) acc[i][j] = fz;

  for (int k0 = 0; k0 < K; k0 += 64) {
    __syncthreads();
#pragma unroll
    for (int it = 0; it < 4; ++it) {
      int rbase = it * 32 + w * 8;
      gld16(A + (size_t)(row0 + rbase + rr) * lda + k0 + scb, (char*)As + rbase * 128);
      gld16(B + (size_t)(col0 + rbase + rr) * ldb + k0 + scb, (char*)Bs + rbase * 128);
    }
    __syncthreads();
#pragma unroll
    for (int kk = 0; kk < 64; kk += 32) {
      bf16x8 af[4], bfr[4];
#pragma unroll
      for (int mi = 0; mi < 4; ++mi) {
        int r = wm * 64 + mi * 16 + lr;
        int off = (r * 128 + (kk + lkb) * 2) ^ ((r & 7) << 4);
        af[mi] = *reinterpret_cast<const bf16x8*>((char*)As + off);
      }
#pragma unroll
      for (int ni = 0; ni < 4; ++ni) {
        int r = wn * 64 + ni * 16 + lr;
        int off = (r * 128 + (kk + lkb) * 2) ^ ((r & 7) << 4);
        bfr[ni] = *reinterpret_cast<const bf16x8*>((char*)Bs + off);
      }
#pragma unroll
      for (int mi = 0; mi < 4; ++mi)
#pragma unroll
        for (int ni = 0; ni < 4; ++ni)
          acc[mi][ni] = mfma16(af[mi], bfr[ni], acc[mi][ni]);
    }
  }
#pragma unroll
  for (int mi = 0; mi < 4; ++mi)
#pragma unroll
    for (int ni = 0; ni < 4; ++ni)
#pragma unroll
      for (int r = 0; r < 4; ++r) {
        int row = row0 + wm * 64 + mi * 16 + (lane >> 4) * 4 + r;
        int col = col0 + wn * 64 + ni * 16 + lr;
        float v = acc[mi][ni][r];
        if (EPI == 5) ((ushort_t*)C)[(size_t)row * N + col] = f2bf(v);
      }
}

// ------------------------------ GEMM 64x128 ---------------------------------
// EPI 2: f32 C + bias + resid.
template <int EPI>
__global__ __launch_bounds__(256)
void gemm64(const ushort_t* __restrict__ A0, const ushort_t* __restrict__ A1,
            const ushort_t* __restrict__ B0, const ushort_t* __restrict__ B1,
            void* __restrict__ C0, void* __restrict__ C1,
            const float* __restrict__ bias, const float* __restrict__ resid,
            int M, int N, int K) {
  __shared__ ushort_t As[64 * 64];
  __shared__ ushort_t Bs[128 * 64];
  const ushort_t* A = blockIdx.z ? A1 : A0;
  const ushort_t* B = blockIdx.z ? B1 : B0;
  void* C = blockIdx.z ? (void*)C1 : (void*)C0;
  const int tid = threadIdx.x;
  const int lane = tid & 63;
  const int w = tid >> 6;
  const int wm = w >> 1, wn = w & 1;
  const int row0 = blockIdx.y * 64, col0 = blockIdx.x * 128;
  const int lr = lane & 15;
  const int lkb = (lane >> 4) * 8;
  const int rr = lane >> 3;
  const int scb = ((lane & 7) ^ rr) * 8;
  const f32x4 fz = {0.f, 0.f, 0.f, 0.f};
  f32x4 acc[2][4];
#pragma unroll
  for (int i = 0; i < 2; ++i)
#pragma unroll
    for (int j = 0; j < 4; ++j) acc[i][j] = fz;

  for (int k0 = 0; k0 < K; k0 += 64) {
    __syncthreads();
#pragma unroll
    for (int it = 0; it < 2; ++it) {
      int rbase = it * 32 + w * 8;
      gld16(A + (size_t)(row0 + rbase + rr) * K + k0 + scb, (char*)As + rbase * 128);
    }
#pragma unroll
    for (int it = 0; it < 4; ++it) {
      int rbase = it * 32 + w * 8;
      gld16(B + (size_t)(col0 + rbase + rr) * K + k0 + scb, (char*)Bs + rbase * 128);
    }
    __syncthreads();
#pragma unroll
    for (int kk = 0; kk < 64; kk += 32) {
      bf16x8 af[2], bfr[4];
#pragma unroll
      for (int mi = 0; mi < 2; ++mi) {
        int r = wm * 32 + mi * 16 + lr;
        int off = (r * 128 + (kk + lkb) * 2) ^ ((r & 7) << 4);
        af[mi] = *reinterpret_cast<const bf16x8*>((char*)As + off);
      }
#pragma unroll
      for (int ni = 0; ni < 4; ++ni) {
        int r = wn * 64 + ni * 16 + lr;
        int off = (r * 128 + (kk + lkb) * 2) ^ ((r & 7) << 4);
        bfr[ni] = *reinterpret_cast<const bf16x8*>((char*)Bs + off);
      }
#pragma unroll
      for (int mi = 0; mi < 2; ++mi)
#pragma unroll
        for (int ni = 0; ni < 4; ++ni)
          acc[mi][ni] = mfma16(af[mi], bfr[ni], acc[mi][ni]);
    }
  }
#pragma unroll
  for (int mi = 0; mi < 2; ++mi)
#pragma unroll
    for (int ni = 0; ni < 4; ++ni)
#pragma unroll
      for (int r = 0; r < 4; ++r) {
        int row = row0 + wm * 32 + mi * 16 + (lane >> 4) * 4 + r;
        int col = col0 + wn * 64 + ni * 16 + lr;
        float v = acc[mi][ni][r];
        if (EPI == 2) {
          v += bias[col] + resid[(size_t)row * N + col];
          ((float*)C)[(size_t)row * N + col] = v;
        }
      }
}

// ------------------------ ffn2 split-K reduce (bf16 partials) ----------------
__global__ __launch_bounds__(256)
void ffn2_red_k(const ushort_t* __restrict__ p0, const ushort_t* __restrict__ p1,
                const float* __restrict__ b2, const float* __restrict__ h,
                float* __restrict__ out) {
  const int row = blockIdx.x;
  const int tid = threadIdx.x;
  const size_t base = (size_t)row * 1024;
  us4 a = reinterpret_cast<const us4*>(p0 + base)[tid];
  us4 b = reinterpret_cast<const us4*>(p1 + base)[tid];
  float4 hv = reinterpret_cast<const float4*>(h + base)[tid];
  float4 bb = reinterpret_cast<const float4*>(b2)[tid];
  float4 o;
  o.x = bf2f(a[0]) + bf2f(b[0]) + hv.x + bb.x;
  o.y = bf2f(a[1]) + bf2f(b[1]) + hv.y + bb.y;
  o.z = bf2f(a[2]) + bf2f(b[2]) + hv.z + bb.z;
  o.w = bf2f(a[3]) + bf2f(b[3]) + hv.w + bb.w;
  reinterpret_cast<float4*>(out + base)[tid] = o;
}

// ----------------------------- attention v4 ---------------------------------
// 8-wave blocks (512 thr), 128-row i-tiles, 512 blocks (2 blocks/CU => 4
// waves/SIMD, double R17's latency hiding). Phase-complement pairing: blocks
// rem and rem+256 (round-robin -> same CU) take tiles 15-q and q (NT sum 36).
// Per-wave math identical to R17 (16 q-rows, swapped-operand MFMA, b64 gather).
__global__ __launch_bounds__(512)
void attn_k(const char* __restrict__ wsb, ushort_t* __restrict__ outp) {
  __shared__ ushort_t Kbuf[2][64 * 64];
  __shared__ ushort_t Vbuf[2][64 * 64];
  __shared__ alignas(16) ushort_t Gs[8][16 * 84];
  __shared__ ushort_t Ps[8][1024];

  const int tid = threadIdx.x;
  const int lane = tid & 63;
  const int w = tid >> 6;                 // 0..7
  const int il = lane & 15;
  const int g = lane >> 4;
  const int lkb = g * 8;
  const int rr = lane >> 3;
  const int scb = ((lane & 7) ^ rr) * 8;

  const int id = (int)blockIdx.x;         // 0..511
  const int phase = id >> 8;
  const int rem = id & 255;
  const int xcd = rem & 7;
  const int ord = rem >> 3;               // 0..31
  const int combo = xcd * 4 + (ord & 3);  // 0..31
  const int q = ord >> 2;                 // 0..7
  const int it = phase ? q : (15 - q);
  const int bn = combo & 15;
  const int dir = combo >> 4;

  const ushort_t* qac  = (const ushort_t*)(wsb + (dir ? O_QAC_B : O_QAC_F));
  const ushort_t* qbd  = (const ushort_t*)(wsb + (dir ? O_QBD_B : O_QBD_F));
  const ushort_t* kkv  = (const ushort_t*)(wsb + (dir ? O_KK_B  : O_KK_F));
  const ushort_t* vtp  = (const ushort_t*)(wsb + (dir ? O_VT_B  : O_VT_F));
  const ushort_t* rkrev= (const ushort_t*)(wsb + (dir ? O_RKREV_B : O_RKREV_F));
  const int colbase = dir ? 512 : 0;

  const size_t hb = (size_t)bn * 2048;
  const size_t vbase = (size_t)bn * 64;
  const size_t nb = (size_t)(bn & 7) * 2048;
  const int b = bn >> 3;
  const int n = bn & 7;

  ushort_t* gw = Gs[w];
  char* pw = (char*)Ps[w];

  const int i0 = it * 128;
  const int NT = 2 * it + 2;
  const int iw0 = i0 + w * 16;            // wave's 16 q-rows

  // wave w stages K row group w*8..w*8+7 and V row group w*8..w*8+7 (1 gld16 each)
  auto STAGE = [&](int bi, int j0) {
    gld16(kkv + (hb + j0 + w * 8 + rr) * 64 + scb, Kbuf[bi] + w * 512);
    gld16(vtp + (vbase + w * 8 + rr) * 2048 + j0 + scb, Vbuf[bi] + w * 512);
  };

  bf16x8 qa[2], qb[2];
#pragma unroll
  for (int kf = 0; kf < 2; ++kf) {
    size_t off = (hb + iw0 + il) * 64 + kf * 32 + lkb;
    qa[kf] = *reinterpret_cast<const bf16x8*>(qac + off);
    qb[kf] = *reinterpret_cast<const bf16x8*>(qbd + off);
  }

  const f32x4 fz = {0.f, 0.f, 0.f, 0.f};
  f32x4 Oa[4];
#pragma unroll
  for (int nf = 0; nf < 4; ++nf) Oa[nf] = fz;
  float lsum = 0.f;

  STAGE(0, 0);
  __syncthreads();
  int cur = 0;
  for (int jt = 0; jt < NT; ++jt) {
    const int j0 = jt * 64;
    if (jt + 1 < NT) STAGE(cur ^ 1, j0 + 64);

    if (j0 <= iw0 + 15) {                  // wave has unmasked rows this step
      bf16x8 bd0[5], bd1[5];
      const int dbase = iw0 - j0 - 63;
#pragma unroll
      for (int ng = 0; ng < 5; ++ng) {
        int d = dbase + ng * 16 + il;
        d = d < 0 ? 0 : (d > 2047 ? 2047 : d);
        const ushort_t* bp = rkrev + (nb + d) * 64 + lkb;
        bd0[ng] = *reinterpret_cast<const bf16x8*>(bp);
        bd1[ng] = *reinterpret_cast<const bf16x8*>(bp + 32);
      }
      const ushort_t* Ks = Kbuf[cur];
      const ushort_t* Vs = Vbuf[cur];
      f32x4 S[4], G[5];
#pragma unroll
      for (int nf = 0; nf < 4; ++nf) S[nf] = fz;
#pragma unroll
      for (int ng = 0; ng < 5; ++ng) G[ng] = fz;
      __builtin_amdgcn_s_setprio(1);
#pragma unroll
      for (int kf = 0; kf < 2; ++kf)
#pragma unroll
        for (int nf = 0; nf < 4; ++nf) {
          int r = nf * 16 + il;
          int off = (r * 128 + (kf * 32 + lkb) * 2) ^ ((r & 7) << 4);
          S[nf] = mfma16(*reinterpret_cast<const bf16x8*>((char*)Ks + off), qa[kf], S[nf]);
        }
#pragma unroll
      for (int ng = 0; ng < 5; ++ng) {
        G[ng] = mfma16(bd0[ng], qb[0], G[ng]);
        G[ng] = mfma16(bd1[ng], qb[1], G[ng]);
      }
      __builtin_amdgcn_s_setprio(0);
#pragma unroll
      for (int ng = 0; ng < 5; ++ng) {
        us4 pk;
        pk[0] = f2bt(G[ng][0]); pk[1] = f2bt(G[ng][1]);
        pk[2] = f2bt(G[ng][2]); pk[3] = f2bt(G[ng][3]);
        *reinterpret_cast<us4*>(gw + il * 84 + ng * 16 + g * 4) = pk;
      }
      const bool full = (j0 + 63 <= iw0);
#pragma unroll
      for (int nf = 0; nf < 4; ++nf) {
        int c3 = il - (nf * 16 + g * 4 + 3) + 63;
        int base4 = c3 & ~3;
        int o = c3 & 3;
        const ushort_t* gp = gw + il * 84 + base4;
        uint64_t av = *reinterpret_cast<const uint64_t*>(gp);
        uint64_t bv2 = *reinterpret_cast<const uint64_t*>(gp + 4);
        uint64_t vv = o ? ((av >> (16 * o)) | (bv2 << (64 - 16 * o))) : av;
#pragma unroll
        for (int r = 0; r < 4; ++r) {
          int jl = nf * 16 + g * 4 + r;
          float sv = S[nf][r] + bf2f((ushort_t)(vv >> (16 * (3 - r))));
          if (!full) sv = (j0 + jl <= iw0 + il) ? sv : -1e30f;
          S[nf][r] = sv;
        }
      }
#pragma unroll
      for (int nf = 0; nf < 4; ++nf) {
        us4 pk;
#pragma unroll
        for (int r = 0; r < 4; ++r) {
          float p = fexp2(S[nf][r]);
          lsum += p;
          pk[r] = f2bt(p);
        }
        int off = (il * 128 + (nf * 16 + g * 4) * 2) ^ ((il & 7) << 4);
        *reinterpret_cast<us4*>(pw + off) = pk;
      }
      __builtin_amdgcn_s_setprio(1);
#pragma unroll
      for (int kf = 0; kf < 2; ++kf) {
        int poff = (il * 128 + (kf * 32 + lkb) * 2) ^ ((il & 7) << 4);
        bf16x8 pt = *reinterpret_cast<const bf16x8*>(pw + poff);
#pragma unroll
        for (int nf = 0; nf < 4; ++nf) {
          int r = nf * 16 + il;
          int voff = (r * 128 + (kf * 32 + lkb) * 2) ^ ((r & 7) << 4);
          Oa[nf] = mfma16(*reinterpret_cast<const bf16x8*>((char*)Vs + voff), pt, Oa[nf]);
        }
      }
      __builtin_amdgcn_s_setprio(0);
    }
    __syncthreads();
    cur ^= 1;
  }
  lsum += __shfl_xor(lsum, 16, 64);
  lsum += __shfl_xor(lsum, 32, 64);
  float invl = 1.f / lsum;
  int ig = iw0 + il;
  int tout = dir ? (2047 - ig) : ig;
  size_t orow = ((size_t)tout * 2 + b) * 1024 + colbase + n * 64;
#pragma unroll
  for (int nf = 0; nf < 4; ++nf) {
    us4 pk;
#pragma unroll
    for (int r = 0; r < 4; ++r) pk[r] = f2bf(Oa[nf][r] * invl);
    *reinterpret_cast<us4*>(outp + orow + nf * 16 + g * 4) = pk;
  }
}

// ------------------------------- host --------------------------------------
extern "C" void kernel_launch(void* const* d_in, const int* in_sizes, int n_in,
                              void* d_out, int out_size, void* d_ws, size_t ws_size,
                              hipStream_t stream) {
  (void)in_sizes; (void)n_in; (void)out_size; (void)ws_size;
  const float* x    = (const float*)d_in[0];
  const float* pos  = (const float*)d_in[1];
  const float* ln1g = (const float*)d_in[4];
  const float* ln1b = (const float*)d_in[5];
  const float* ln2g = (const float*)d_in[6];
  const float* ln2b = (const float*)d_in[7];
  const float* ln3g = (const float*)d_in[8];
  const float* ln3b = (const float*)d_in[9];
  const float* qkvf = (const float*)d_in[10];
  const float* rnetf= (const float*)d_in[11];
  const float* rwbf = (const float*)d_in[12];
  const float* rrbf = (const float*)d_in[13];
  const float* qkvb = (const float*)d_in[14];
  const float* rnetb= (const float*)d_in[15];
  const float* rwbb = (const float*)d_in[16];
  const float* rrbb = (const float*)d_in[17];
  const float* wo   = (const float*)d_in[18];
  const float* bo   = (const float*)d_in[19];
  const float* w1   = (const float*)d_in[20];
  const float* b1   = (const float*)d_in[21];
  const float* w2   = (const float*)d_in[22];
  const float* b2   = (const float*)d_in[23];
  float* out = (float*)d_out;
  char* ws = (char*)d_ws;
  auto U = [&](size_t off) { return (ushort_t*)(ws + off); };

  // prep: all weight conversions + dual LN in one launch
  PrepArgs pa;
  const float* srcs[8] = {qkvf, qkvb, rnetf, rnetb, wo, w1, w2, pos};
  size_t dsts[8] = {O_QKV_F, O_QKV_B, O_RNET_F, O_RNET_B, O_WO, O_W1, O_W2, O_POS};
  int bl[8] = {1536, 1536, 512, 512, 1024, 4096, 4096, 2048};
  int cum = 0;
  for (int s = 0; s < 8; ++s) {
    pa.src[s] = srcs[s];
    pa.dst[s] = U(dsts[s]);
    pa.bstart[s] = cum;
    cum += bl[s];
  }
  pa.cvt_blocks = cum;
  pa.x = x; pa.g1 = ln1g; pa.b1 = ln1b; pa.g2 = ln2g; pa.b2 = ln2b;
  pa.o1 = U(O_LN1); pa.o2 = U(O_LN2);
  prep_k<<<dim3(cum + 4096), dim3(256), 0, stream>>>(pa);

  // merged QKV (fused post, v->vt) + rk (fused reverse): flat 896-block launch
  qkvrk_k<<<dim3(896), dim3(256), 0, stream>>>(
      U(O_LN1), U(O_LN2), U(O_POS),
      U(O_QKV_F), U(O_QKV_B), U(O_RNET_F), U(O_RNET_B),
      ws, rwbf, rrbf, rwbb, rrbb);

  attn_k<<<dim3(512), dim3(512), 0, stream>>>(ws, U(O_ACAT));

  gemm64<2><<<dim3(8, 64, 1), dim3(256), 0, stream>>>(
      U(O_ACAT), U(O_ACAT), U(O_WO), U(O_WO), ws + O_H, ws + O_H,
      bo, x, 4096, 1024, 1024);

  ln_one_k<<<dim3(4096), dim3(256), 0, stream>>>((const float*)(ws + O_H), ln3g, ln3b, U(O_LN3));
  gemm_bt<1><<<dim3(32, 32), dim3(256), 0, stream>>>(U(O_LN3), U(O_W1), U(O_FFNM), b1, nullptr, 4096, 4096, 1024);

  // ffn2: 128x128 split-K=2 (z = K-half), bf16 partials, then fused reduce
  ushort_t* part0 = U(O_FPART);
  ushort_t* part1 = U(O_FPART + 8388608);
  gemm_bt2<5><<<dim3(8, 32, 2), dim3(256), 0, stream>>>(
      U(O_FFNM), U(O_FFNM) + 2048, U(O_W2), U(O_W2) + 2048, part0, part1,
      4096, 1024, 2048, 4096, 4096);
  ffn2_red_k<<<dim3(4096), dim3(256), 0, stream>>>(
      part0, part1, b2, (const float*)(ws + O_H), out);
}

// Round 20
// 306.191 us; speedup vs baseline: 1.1764x; 1.1764x over previous
//
#include <hip/hip_runtime.h>
#include <cstdint>
#include <cstddef>

// ---------------------------------------------------------------------------
// RelativeTransformerEncoderLayer on MI355X (gfx950)
// T=2048 B=2 D=1024 NH=8 DH=64 DFF=4096
// Final configuration (R18): 549.8 -> 307.0 us over the session.
// ---------------------------------------------------------------------------

typedef unsigned short ushort_t;
typedef __bf16 bf16x8 __attribute__((ext_vector_type(8)));
typedef float f32x4 __attribute__((ext_vector_type(4)));
typedef unsigned short us8 __attribute__((ext_vector_type(8)));
typedef unsigned short us4 __attribute__((ext_vector_type(4)));

#define DEV static __device__ __forceinline__

DEV ushort_t f2bf(float x) {
  union { float f; unsigned u; } v; v.f = x;
  unsigned r = (v.u + 0x7FFFu + ((v.u >> 16) & 1u)) >> 16;
  return (ushort_t)r;
}
DEV ushort_t f2bt(float x) {              // truncating (internal use)
  union { float f; unsigned u; } v; v.f = x;
  return (ushort_t)(v.u >> 16);
}
DEV float bf2f(ushort_t h) {
  union { unsigned u; float f; } v; v.u = ((unsigned)h) << 16;
  return v.f;
}
DEV float fexp2(float x) { float r; asm("v_exp_f32 %0, %1" : "=v"(r) : "v"(x)); return r; }
DEV f32x4 mfma16(bf16x8 a, bf16x8 b, f32x4 c) {
  return __builtin_amdgcn_mfma_f32_16x16x32_bf16(a, b, c, 0, 0, 0);
}
// async global->LDS, 16B per lane; dest = wave-uniform base + lane*16 (linear).
DEV void gld16(const void* g, void* l) {
  __builtin_amdgcn_global_load_lds((const __attribute__((address_space(1))) void*)g,
                                   (__attribute__((address_space(3))) void*)l,
                                   16, 0, 0);
}

constexpr float SCLQ = 0.125f * 1.44269504088896f;   // 1/sqrt(64) * log2(e)

// ---------------- workspace layout (bytes) ----------------
constexpr size_t O_QKV_F  = 0;
constexpr size_t O_QKV_B  = 3145728;
constexpr size_t O_RNET_F = 6291456;
constexpr size_t O_RNET_B = 7340032;
constexpr size_t O_WO     = 8388608;
constexpr size_t O_W1     = 10485760;
constexpr size_t O_W2     = 18874368;
constexpr size_t O_RKREV_F= 27262976;
constexpr size_t O_RKREV_B= 29360128;
constexpr size_t O_QAC_F  = 31457280;
constexpr size_t O_QBD_F  = 35651584;
constexpr size_t O_KK_F   = 39845888;
constexpr size_t O_VT_F   = 44040192;
constexpr size_t O_QAC_B  = 48234496;
constexpr size_t O_QBD_B  = 52428800;
constexpr size_t O_KK_B   = 56623104;
constexpr size_t O_VT_B   = 60817408;
constexpr size_t O_H      = 65011712;
constexpr size_t O_LN3    = 81788928;
constexpr size_t ZONE     = 90177536;
constexpr size_t O_POS    = ZONE + 0;
constexpr size_t O_LN1    = ZONE + 4194304;
constexpr size_t O_LN2    = ZONE + 12582912;
constexpr size_t O_HEADS_F= ZONE + 20971520;
constexpr size_t O_HEADS_B= ZONE + 33554432;
constexpr size_t O_ACAT   = ZONE + 0;
constexpr size_t O_FFNM   = ZONE + 8388608;
// ffn2 split-K bf16 partials: overlay dead attention operand region (8MB each)
constexpr size_t O_FPART  = O_QAC_F;

// --------------------- merged prep: cvt (8 segs) + ln_dual -------------------
struct PrepArgs {
  const float* src[8];
  ushort_t* dst[8];
  int bstart[8];
  int cvt_blocks;
  const float* x;
  const float* g1; const float* b1;
  const float* g2; const float* b2;
  ushort_t* o1; ushort_t* o2;
};
__global__ __launch_bounds__(256)
void prep_k(PrepArgs a) {
  __shared__ float sbuf[8];
  const int bx = blockIdx.x;
  const int tid = threadIdx.x;
  if (bx < a.cvt_blocks) {
    int s = 0;
#pragma unroll
    for (int k = 1; k < 8; ++k) if (bx >= a.bstart[k]) s = k;
    int i = (bx - a.bstart[s]) * 256 + tid;
    float4 v = reinterpret_cast<const float4*>(a.src[s])[i];
    us4 o; o[0] = f2bf(v.x); o[1] = f2bf(v.y); o[2] = f2bf(v.z); o[3] = f2bf(v.w);
    reinterpret_cast<us4*>(a.dst[s])[i] = o;
    return;
  }
  const int row = bx - a.cvt_blocks;
  const float* xr = a.x + (size_t)row * 1024;
  float4 v = reinterpret_cast<const float4*>(xr)[tid];
  float s  = v.x + v.y + v.z + v.w;
  float s2 = v.x*v.x + v.y*v.y + v.z*v.z + v.w*v.w;
  for (int m = 32; m >= 1; m >>= 1) { s += __shfl_xor(s, m, 64); s2 += __shfl_xor(s2, m, 64); }
  int w = tid >> 6;
  if ((tid & 63) == 0) { sbuf[w] = s; sbuf[4 + w] = s2; }
  __syncthreads();
  float S  = sbuf[0] + sbuf[1] + sbuf[2] + sbuf[3];
  float S2 = sbuf[4] + sbuf[5] + sbuf[6] + sbuf[7];
  float mu  = S * (1.f / 1024.f);
  float var = S2 * (1.f / 1024.f) - mu * mu;
  float inv = rsqrtf(var + 1e-5f);
  int t = row >> 1, b = row & 1;
  size_t r2 = ((size_t)(2047 - t) * 2 + b) * 1024;
  float4 G1 = reinterpret_cast<const float4*>(a.g1)[tid];
  float4 B1 = reinterpret_cast<const float4*>(a.b1)[tid];
  float4 G2 = reinterpret_cast<const float4*>(a.g2)[tid];
  float4 B2 = reinterpret_cast<const float4*>(a.b2)[tid];
  float n0 = (v.x - mu) * inv, n1 = (v.y - mu) * inv, n2 = (v.z - mu) * inv, n3 = (v.w - mu) * inv;
  us4 aa, c;
  aa[0] = f2bf(n0 * G1.x + B1.x); aa[1] = f2bf(n1 * G1.y + B1.y);
  aa[2] = f2bf(n2 * G1.z + B1.z); aa[3] = f2bf(n3 * G1.w + B1.w);
  c[0] = f2bf(n0 * G2.x + B2.x); c[1] = f2bf(n1 * G2.y + B2.y);
  c[2] = f2bf(n2 * G2.z + B2.z); c[3] = f2bf(n3 * G2.w + B2.w);
  reinterpret_cast<us4*>(a.o1 + (size_t)row * 1024)[tid] = aa;
  reinterpret_cast<us4*>(a.o2 + r2)[tid] = c;
}

// -------------------------- LayerNorm (single) ------------------------------
__global__ __launch_bounds__(256)
void ln_one_k(const float* __restrict__ x,
              const float* __restrict__ g1, const float* __restrict__ b1,
              ushort_t* __restrict__ o1) {
  __shared__ float sbuf[8];
  const int row = blockIdx.x;
  const int tid = threadIdx.x;
  const float* xr = x + (size_t)row * 1024;
  float4 v = reinterpret_cast<const float4*>(xr)[tid];
  float s  = v.x + v.y + v.z + v.w;
  float s2 = v.x*v.x + v.y*v.y + v.z*v.z + v.w*v.w;
  for (int m = 32; m >= 1; m >>= 1) { s += __shfl_xor(s, m, 64); s2 += __shfl_xor(s2, m, 64); }
  int w = tid >> 6;
  if ((tid & 63) == 0) { sbuf[w] = s; sbuf[4 + w] = s2; }
  __syncthreads();
  float S  = sbuf[0] + sbuf[1] + sbuf[2] + sbuf[3];
  float S2 = sbuf[4] + sbuf[5] + sbuf[6] + sbuf[7];
  float mu  = S * (1.f / 1024.f);
  float var = S2 * (1.f / 1024.f) - mu * mu;
  float inv = rsqrtf(var + 1e-5f);
  float4 G1 = reinterpret_cast<const float4*>(g1)[tid];
  float4 B1 = reinterpret_cast<const float4*>(b1)[tid];
  us4 a;
  a[0] = f2bf((v.x - mu) * inv * G1.x + B1.x);
  a[1] = f2bf((v.y - mu) * inv * G1.y + B1.y);
  a[2] = f2bf((v.z - mu) * inv * G1.z + B1.z);
  a[3] = f2bf((v.w - mu) * inv * G1.w + B1.w);
  reinterpret_cast<us4*>(o1 + (size_t)row * 1024)[tid] = a;
}

// ------------------------------ GEMM 128x128 --------------------------------
template <int EPI>
__global__ __launch_bounds__(256)
void gemm_bt(const ushort_t* __restrict__ A, const ushort_t* __restrict__ B,
             void* __restrict__ C, const float* __restrict__ bias,
             const float* __restrict__ resid, int M, int N, int K) {
  __shared__ ushort_t As[128 * 64];
  __shared__ ushort_t Bs[128 * 64];
  const int tid = threadIdx.x;
  const int lane = tid & 63;
  const int w = tid >> 6;
  const int wm = w >> 1, wn = w & 1;
  const int row0 = blockIdx.y * 128, col0 = blockIdx.x * 128;
  const int lr = lane & 15;
  const int lkb = (lane >> 4) * 8;
  const int rr = lane >> 3;
  const int scb = ((lane & 7) ^ rr) * 8;
  const f32x4 fz = {0.f, 0.f, 0.f, 0.f};
  f32x4 acc[4][4];
#pragma unroll
  for (int i = 0; i < 4; ++i)
#pragma unroll
    for (int j = 0; j < 4; ++j) acc[i][j] = fz;

  for (int k0 = 0; k0 < K; k0 += 64) {
    __syncthreads();
#pragma unroll
    for (int it = 0; it < 4; ++it) {
      int rbase = it * 32 + w * 8;
      gld16(A + (size_t)(row0 + rbase + rr) * K + k0 + scb, (char*)As + rbase * 128);
      gld16(B + (size_t)(col0 + rbase + rr) * K + k0 + scb, (char*)Bs + rbase * 128);
    }
    __syncthreads();
#pragma unroll
    for (int kk = 0; kk < 64; kk += 32) {
      bf16x8 af[4], bfr[4];
#pragma unroll
      for (int mi = 0; mi < 4; ++mi) {
        int r = wm * 64 + mi * 16 + lr;
        int off = (r * 128 + (kk + lkb) * 2) ^ ((r & 7) << 4);
        af[mi] = *reinterpret_cast<const bf16x8*>((char*)As + off);
      }
#pragma unroll
      for (int ni = 0; ni < 4; ++ni) {
        int r = wn * 64 + ni * 16 + lr;
        int off = (r * 128 + (kk + lkb) * 2) ^ ((r & 7) << 4);
        bfr[ni] = *reinterpret_cast<const bf16x8*>((char*)Bs + off);
      }
#pragma unroll
      for (int mi = 0; mi < 4; ++mi)
#pragma unroll
        for (int ni = 0; ni < 4; ++ni)
          acc[mi][ni] = mfma16(af[mi], bfr[ni], acc[mi][ni]);
    }
  }
#pragma unroll
  for (int mi = 0; mi < 4; ++mi)
#pragma unroll
    for (int ni = 0; ni < 4; ++ni)
#pragma unroll
      for (int r = 0; r < 4; ++r) {
        int row = row0 + wm * 64 + mi * 16 + (lane >> 4) * 4 + r;
        int col = col0 + wn * 64 + ni * 16 + lr;
        float v = acc[mi][ni][r];
        if (EPI == 0) {
          ((ushort_t*)C)[(size_t)row * N + col] = f2bf(v);
        } else if (EPI == 1) {
          v += bias[col]; v = v > 0.f ? v : 0.f;
          ((ushort_t*)C)[(size_t)row * N + col] = f2bf(v);
        } else {
          v += bias[col] + resid[(size_t)row * N + col];
          ((float*)C)[(size_t)row * N + col] = v;
        }
      }
}

// ----------------- merged QKV (fused post) + rk (fused reverse) --------------
// Flat 1D grid of 896 active blocks: id<768 -> qkv (z=id/384; 12x32 tiles);
// id>=768 -> rk (z=2+(id-768)/64; 4x16 tiles). No no-op blocks.
__global__ __launch_bounds__(256)
void qkvrk_k(const ushort_t* __restrict__ A0, const ushort_t* __restrict__ A1,
             const ushort_t* __restrict__ A2,
             const ushort_t* __restrict__ B0, const ushort_t* __restrict__ B1,
             const ushort_t* __restrict__ B2, const ushort_t* __restrict__ B3,
             char* __restrict__ wsb,
             const float* __restrict__ rw0, const float* __restrict__ rr0,
             const float* __restrict__ rw1, const float* __restrict__ rr1) {
  const int id = (int)blockIdx.x;
  int z, bxx, byy;
  if (id < 768) {
    z = id / 384;
    int rem = id - z * 384;
    bxx = rem % 12;
    byy = rem / 12;
  } else {
    int id2 = id - 768;
    z = 2 + (id2 >> 6);
    int rem = id2 & 63;
    bxx = rem & 3;
    byy = rem >> 2;
  }
  const ushort_t* A = (z == 0) ? A0 : (z == 1) ? A1 : A2;
  const ushort_t* B = (z == 0) ? B0 : (z == 1) ? B1 : (z == 2) ? B2 : B3;

  __shared__ ushort_t As[128 * 64];
  __shared__ ushort_t Bs[128 * 64];
  const int tid = threadIdx.x;
  const int lane = tid & 63;
  const int w = tid >> 6;
  const int wm = w >> 1, wn = w & 1;
  const int row0 = byy * 128, col0 = bxx * 128;
  const int lr = lane & 15;
  const int lkb = (lane >> 4) * 8;
  const int rr = lane >> 3;
  const int scb = ((lane & 7) ^ rr) * 8;
  const f32x4 fz = {0.f, 0.f, 0.f, 0.f};
  f32x4 acc[4][4];
#pragma unroll
  for (int i = 0; i < 4; ++i)
#pragma unroll
    for (int j = 0; j < 4; ++j) acc[i][j] = fz;

  for (int k0 = 0; k0 < 1024; k0 += 64) {
    __syncthreads();
#pragma unroll
    for (int it = 0; it < 4; ++it) {
      int rbase = it * 32 + w * 8;
      gld16(A + (size_t)(row0 + rbase + rr) * 1024 + k0 + scb, (char*)As + rbase * 128);
      gld16(B + (size_t)(col0 + rbase + rr) * 1024 + k0 + scb, (char*)Bs + rbase * 128);
    }
    __syncthreads();
#pragma unroll
    for (int kk = 0; kk < 64; kk += 32) {
      bf16x8 af[4], bfr[4];
#pragma unroll
      for (int mi = 0; mi < 4; ++mi) {
        int r = wm * 64 + mi * 16 + lr;
        int off = (r * 128 + (kk + lkb) * 2) ^ ((r & 7) << 4);
        af[mi] = *reinterpret_cast<const bf16x8*>((char*)As + off);
      }
#pragma unroll
      for (int ni = 0; ni < 4; ++ni) {
        int r = wn * 64 + ni * 16 + lr;
        int off = (r * 128 + (kk + lkb) * 2) ^ ((r & 7) << 4);
        bfr[ni] = *reinterpret_cast<const bf16x8*>((char*)Bs + off);
      }
#pragma unroll
      for (int mi = 0; mi < 4; ++mi)
#pragma unroll
        for (int ni = 0; ni < 4; ++ni)
          acc[mi][ni] = mfma16(af[mi], bfr[ni], acc[mi][ni]);
    }
  }
  const int dirz = z & 1;
  const float* rwb = dirz ? rw1 : rw0;
  const float* rrb = dirz ? rr1 : rr0;
#pragma unroll
  for (int mi = 0; mi < 4; ++mi)
#pragma unroll
    for (int ni = 0; ni < 4; ++ni)
#pragma unroll
      for (int r = 0; r < 4; ++r) {
        int row = row0 + wm * 64 + mi * 16 + (lane >> 4) * 4 + r;
        int col = col0 + wn * 64 + ni * 16 + lr;
        float v = acc[mi][ni][r];
        if (z < 2) {        // qkv fused post-process
          int t = row >> 1, bb = row & 1;
          if (col < 512) {
            int nn = col >> 6, dh = col & 63;
            ushort_t* q_ac = (ushort_t*)(wsb + (dirz ? O_QAC_B : O_QAC_F));
            ushort_t* q_bd = (ushort_t*)(wsb + (dirz ? O_QBD_B : O_QBD_F));
            size_t o = ((size_t)(bb * 8 + nn) * 2048 + t) * 64 + dh;
            q_ac[o] = f2bf((v + rwb[col]) * SCLQ);
            q_bd[o] = f2bf((v + rrb[col]) * SCLQ);
          } else if (col < 1024) {
            int cc = col - 512;
            int nn = cc >> 6, dh = cc & 63;
            ushort_t* kout = (ushort_t*)(wsb + (dirz ? O_KK_B : O_KK_F));
            kout[((size_t)(bb * 8 + nn) * 2048 + t) * 64 + dh] = f2bf(v);
          } else {
            ushort_t* hv = (ushort_t*)(wsb + (dirz ? O_HEADS_B : O_HEADS_F));
            hv[(size_t)row * 1536 + col] = f2bf(v);
          }
        } else {            // rk fused reverse
          ushort_t* rkrev = (ushort_t*)(wsb + (dirz ? O_RKREV_B : O_RKREV_F));
          int nn = col >> 6, dh = col & 63;
          rkrev[((size_t)nn * 2048 + (2047 - row)) * 64 + dh] = f2bf(v);
        }
      }
}

// ------------------------- GEMM 128x128, z-dispatch --------------------------
// EPI 5: bf16 partial store (split-K). lda/ldb row strides (elements).
template <int EPI>
__global__ __launch_bounds__(256)
void gemm_bt2(const ushort_t* __restrict__ A0, const ushort_t* __restrict__ A1,
              const ushort_t* __restrict__ B0, const ushort_t* __restrict__ B1,
              void* __restrict__ C0, void* __restrict__ C1,
              int M, int N, int K, int lda, int ldb) {
  __shared__ ushort_t As[128 * 64];
  __shared__ ushort_t Bs[128 * 64];
  const ushort_t* A = blockIdx.z ? A1 : A0;
  const ushort_t* B = blockIdx.z ? B1 : B0;
  void* C = blockIdx.z ? (void*)C1 : (void*)C0;
  const int tid = threadIdx.x;
  const int lane = tid & 63;
  const int w = tid >> 6;
  const int wm = w >> 1, wn = w & 1;
  const int row0 = blockIdx.y * 128, col0 = blockIdx.x * 128;
  const int lr = lane & 15;
  const int lkb = (lane >> 4) * 8;
  const int rr = lane >> 3;
  const int scb = ((lane & 7) ^ rr) * 8;
  const f32x4 fz = {0.f, 0.f, 0.f, 0.f};
  f32x4 acc[4][4];
#pragma unroll
  for (int i = 0; i < 4; ++i)
#pragma unroll
    for (int j = 0; j < 4; ++j) acc[i][j] = fz;

  for (int k0 = 0; k0 < K; k0 += 64) {
    __syncthreads();
#pragma unroll
    for (int it = 0; it < 4; ++it) {
      int rbase = it * 32 + w * 8;
      gld16(A + (size_t)(row0 + rbase + rr) * lda + k0 + scb, (char*)As + rbase * 128);
      gld16(B + (size_t)(col0 + rbase + rr) * ldb + k0 + scb, (char*)Bs + rbase * 128);
    }
    __syncthreads();
#pragma unroll
    for (int kk = 0; kk < 64; kk += 32) {
      bf16x8 af[4], bfr[4];
#pragma unroll
      for (int mi = 0; mi < 4; ++mi) {
        int r = wm * 64 + mi * 16 + lr;
        int off = (r * 128 + (kk + lkb) * 2) ^ ((r & 7) << 4);
        af[mi] = *reinterpret_cast<const bf16x8*>((char*)As + off);
      }
#pragma unroll
      for (int ni = 0; ni < 4; ++ni) {
        int r = wn * 64 + ni * 16 + lr;
        int off = (r * 128 + (kk + lkb) * 2) ^ ((r & 7) << 4);
        bfr[ni] = *reinterpret_cast<const bf16x8*>((char*)Bs + off);
      }
#pragma unroll
      for (int mi = 0; mi < 4; ++mi)
#pragma unroll
        for (int ni = 0; ni < 4; ++ni)
          acc[mi][ni] = mfma16(af[mi], bfr[ni], acc[mi][ni]);
    }
  }
#pragma unroll
  for (int mi = 0; mi < 4; ++mi)
#pragma unroll
    for (int ni = 0; ni < 4; ++ni)
#pragma unroll
      for (int r = 0; r < 4; ++r) {
        int row = row0 + wm * 64 + mi * 16 + (lane >> 4) * 4 + r;
        int col = col0 + wn * 64 + ni * 16 + lr;
        float v = acc[mi][ni][r];
        if (EPI == 5) ((ushort_t*)C)[(size_t)row * N + col] = f2bf(v);
      }
}

// ------------------------------ GEMM 64x128 ---------------------------------
// EPI 2: f32 C + bias + resid.
template <int EPI>
__global__ __launch_bounds__(256)
void gemm64(const ushort_t* __restrict__ A0, const ushort_t* __restrict__ A1,
            const ushort_t* __restrict__ B0, const ushort_t* __restrict__ B1,
            void* __restrict__ C0, void* __restrict__ C1,
            const float* __restrict__ bias, const float* __restrict__ resid,
            int M, int N, int K) {
  __shared__ ushort_t As[64 * 64];
  __shared__ ushort_t Bs[128 * 64];
  const ushort_t* A = blockIdx.z ? A1 : A0;
  const ushort_t* B = blockIdx.z ? B1 : B0;
  void* C = blockIdx.z ? (void*)C1 : (void*)C0;
  const int tid = threadIdx.x;
  const int lane = tid & 63;
  const int w = tid >> 6;
  const int wm = w >> 1, wn = w & 1;
  const int row0 = blockIdx.y * 64, col0 = blockIdx.x * 128;
  const int lr = lane & 15;
  const int lkb = (lane >> 4) * 8;
  const int rr = lane >> 3;
  const int scb = ((lane & 7) ^ rr) * 8;
  const f32x4 fz = {0.f, 0.f, 0.f, 0.f};
  f32x4 acc[2][4];
#pragma unroll
  for (int i = 0; i < 2; ++i)
#pragma unroll
    for (int j = 0; j < 4; ++j) acc[i][j] = fz;

  for (int k0 = 0; k0 < K; k0 += 64) {
    __syncthreads();
#pragma unroll
    for (int it = 0; it < 2; ++it) {
      int rbase = it * 32 + w * 8;
      gld16(A + (size_t)(row0 + rbase + rr) * K + k0 + scb, (char*)As + rbase * 128);
    }
#pragma unroll
    for (int it = 0; it < 4; ++it) {
      int rbase = it * 32 + w * 8;
      gld16(B + (size_t)(col0 + rbase + rr) * K + k0 + scb, (char*)Bs + rbase * 128);
    }
    __syncthreads();
#pragma unroll
    for (int kk = 0; kk < 64; kk += 32) {
      bf16x8 af[2], bfr[4];
#pragma unroll
      for (int mi = 0; mi < 2; ++mi) {
        int r = wm * 32 + mi * 16 + lr;
        int off = (r * 128 + (kk + lkb) * 2) ^ ((r & 7) << 4);
        af[mi] = *reinterpret_cast<const bf16x8*>((char*)As + off);
      }
#pragma unroll
      for (int ni = 0; ni < 4; ++ni) {
        int r = wn * 64 + ni * 16 + lr;
        int off = (r * 128 + (kk + lkb) * 2) ^ ((r & 7) << 4);
        bfr[ni] = *reinterpret_cast<const bf16x8*>((char*)Bs + off);
      }
#pragma unroll
      for (int mi = 0; mi < 2; ++mi)
#pragma unroll
        for (int ni = 0; ni < 4; ++ni)
          acc[mi][ni] = mfma16(af[mi], bfr[ni], acc[mi][ni]);
    }
  }
#pragma unroll
  for (int mi = 0; mi < 2; ++mi)
#pragma unroll
    for (int ni = 0; ni < 4; ++ni)
#pragma unroll
      for (int r = 0; r < 4; ++r) {
        int row = row0 + wm * 32 + mi * 16 + (lane >> 4) * 4 + r;
        int col = col0 + wn * 64 + ni * 16 + lr;
        float v = acc[mi][ni][r];
        if (EPI == 2) {
          v += bias[col] + resid[(size_t)row * N + col];
          ((float*)C)[(size_t)row * N + col] = v;
        }
      }
}

// ------------------------ ffn2 split-K reduce (bf16 partials) ----------------
__global__ __launch_bounds__(256)
void ffn2_red_k(const ushort_t* __restrict__ p0, const ushort_t* __restrict__ p1,
                const float* __restrict__ b2, const float* __restrict__ h,
                float* __restrict__ out) {
  const int row = blockIdx.x;
  const int tid = threadIdx.x;
  const size_t base = (size_t)row * 1024;
  us4 a = reinterpret_cast<const us4*>(p0 + base)[tid];
  us4 b = reinterpret_cast<const us4*>(p1 + base)[tid];
  float4 hv = reinterpret_cast<const float4*>(h + base)[tid];
  float4 bb = reinterpret_cast<const float4*>(b2)[tid];
  float4 o;
  o.x = bf2f(a[0]) + bf2f(b[0]) + hv.x + bb.x;
  o.y = bf2f(a[1]) + bf2f(b[1]) + hv.y + bb.y;
  o.z = bf2f(a[2]) + bf2f(b[2]) + hv.z + bb.z;
  o.w = bf2f(a[3]) + bf2f(b[3]) + hv.w + bb.w;
  reinterpret_cast<float4*>(out + base)[tid] = o;
}

// --------------------------- V transpose (both dirs) ------------------------
__global__ __launch_bounds__(256)
void v_trans2_k(const ushort_t* __restrict__ hf, const ushort_t* __restrict__ hb2,
                char* __restrict__ wsb) {
  __shared__ float tile[64][65];
  const int dir = blockIdx.z;
  const ushort_t* heads = dir ? hb2 : hf;
  ushort_t* vt = (ushort_t*)(wsb + (dir ? O_VT_B : O_VT_F));
  int tt0 = blockIdx.x * 64;
  int bn = blockIdx.y;
  int b = bn >> 3, n = bn & 7;
  int tid = threadIdx.x;
#pragma unroll
  for (int i = 0; i < 16; ++i) {
    int rr = i * 4 + (tid >> 6);
    int cc = tid & 63;
    tile[rr][cc] = bf2f(heads[(size_t)((tt0 + rr) * 2 + b) * 1536 + 1024 + n * 64 + cc]);
  }
  __syncthreads();
#pragma unroll
  for (int i = 0; i < 16; ++i) {
    int dh = i * 4 + (tid >> 6);
    int tt = tid & 63;
    vt[((size_t)bn * 64 + dh) * 2048 + tt0 + tt] = f2bf(tile[tt][dh]);
  }
}

// ----------------------------- attention (best: R17/R18) --------------------
__global__ __launch_bounds__(256)
void attn_k(const char* __restrict__ wsb, ushort_t* __restrict__ outp) {
  __shared__ ushort_t Kbuf[2][64 * 64];
  __shared__ ushort_t Vbuf[2][64 * 64];
  __shared__ alignas(16) ushort_t Gs[4][16 * 84];
  __shared__ ushort_t Ps[4][1024];

  const int tid = threadIdx.x;
  const int lane = tid & 63;
  const int w = tid >> 6;
  const int il = lane & 15;
  const int g = lane >> 4;
  const int lkb = g * 8;
  const int rr = lane >> 3;
  const int scb = ((lane & 7) ^ rr) * 8;

  const int id = (int)(blockIdx.x + (blockIdx.y << 4) + (blockIdx.z << 8));
  const int xcd = id & 7;
  const int ord = id >> 3;
  const int pair = xcd * 4 + (ord & 3);
  const int bx = ord >> 2;
  const int bn = pair & 15;
  const int dir = pair >> 4;

  const ushort_t* qac  = (const ushort_t*)(wsb + (dir ? O_QAC_B : O_QAC_F));
  const ushort_t* qbd  = (const ushort_t*)(wsb + (dir ? O_QBD_B : O_QBD_F));
  const ushort_t* kkv  = (const ushort_t*)(wsb + (dir ? O_KK_B  : O_KK_F));
  const ushort_t* vtp  = (const ushort_t*)(wsb + (dir ? O_VT_B  : O_VT_F));
  const ushort_t* rkrev= (const ushort_t*)(wsb + (dir ? O_RKREV_B : O_RKREV_F));
  const int colbase = dir ? 512 : 0;

  const size_t hb = (size_t)bn * 2048;
  const size_t vbase = (size_t)bn * 64;
  const size_t nb = (size_t)(bn & 7) * 2048;
  const int b = bn >> 3;
  const int n = bn & 7;

  ushort_t* gw = Gs[w];
  char* pw = (char*)Ps[w];

  for (int half = 0; half < 2; ++half) {
    const int it = half ? bx : (31 - bx);
    const int i0 = it * 64;
    const int NT = it + 1;
    const int iw0 = i0 + w * 16;

    auto STAGE = [&](int bi, int j0) {
      ushort_t* kb = Kbuf[bi] + w * 512;
      ushort_t* vbp = Vbuf[bi] + w * 512;
      gld16(kkv + (hb + j0 + w * 8 + rr) * 64 + scb, kb);
      gld16(kkv + (hb + j0 + 32 + w * 8 + rr) * 64 + scb, kb + 2048);
      gld16(vtp + (vbase + w * 8 + rr) * 2048 + j0 + scb, vbp);
      gld16(vtp + (vbase + 32 + w * 8 + rr) * 2048 + j0 + scb, vbp + 2048);
    };

    bf16x8 qa[2], qb[2];
#pragma unroll
    for (int kf = 0; kf < 2; ++kf) {
      size_t off = (hb + iw0 + il) * 64 + kf * 32 + lkb;
      qa[kf] = *reinterpret_cast<const bf16x8*>(qac + off);
      qb[kf] = *reinterpret_cast<const bf16x8*>(qbd + off);
    }

    const f32x4 fz = {0.f, 0.f, 0.f, 0.f};
    f32x4 Oa[4];
#pragma unroll
    for (int nf = 0; nf < 4; ++nf) Oa[nf] = fz;
    float lsum = 0.f;

    STAGE(0, 0);
    __syncthreads();
    int cur = 0;
    for (int jt = 0; jt < NT; ++jt) {
      const int j0 = jt * 64;

      bf16x8 bd0[5], bd1[5];
      const int dbase = iw0 - j0 - 63;
#pragma unroll
      for (int ng = 0; ng < 5; ++ng) {
        int d = dbase + ng * 16 + il;
        d = d < 0 ? 0 : (d > 2047 ? 2047 : d);
        const ushort_t* bp = rkrev + (nb + d) * 64 + lkb;
        bd0[ng] = *reinterpret_cast<const bf16x8*>(bp);
        bd1[ng] = *reinterpret_cast<const bf16x8*>(bp + 32);
      }
      if (jt + 1 < NT) STAGE(cur ^ 1, j0 + 64);

      const ushort_t* Ks = Kbuf[cur];
      const ushort_t* Vs = Vbuf[cur];
      f32x4 S[4], G[5];
#pragma unroll
      for (int nf = 0; nf < 4; ++nf) S[nf] = fz;
#pragma unroll
      for (int ng = 0; ng < 5; ++ng) G[ng] = fz;
      __builtin_amdgcn_s_setprio(1);
#pragma unroll
      for (int kf = 0; kf < 2; ++kf)
#pragma unroll
        for (int nf = 0; nf < 4; ++nf) {
          int r = nf * 16 + il;
          int off = (r * 128 + (kf * 32 + lkb) * 2) ^ ((r & 7) << 4);
          S[nf] = mfma16(*reinterpret_cast<const bf16x8*>((char*)Ks + off), qa[kf], S[nf]);
        }
#pragma unroll
      for (int ng = 0; ng < 5; ++ng) {
        G[ng] = mfma16(bd0[ng], qb[0], G[ng]);
        G[ng] = mfma16(bd1[ng], qb[1], G[ng]);
      }
      __builtin_amdgcn_s_setprio(0);
#pragma unroll
      for (int ng = 0; ng < 5; ++ng) {
        us4 pk;
        pk[0] = f2bt(G[ng][0]); pk[1] = f2bt(G[ng][1]);
        pk[2] = f2bt(G[ng][2]); pk[3] = f2bt(G[ng][3]);
        *reinterpret_cast<us4*>(gw + il * 84 + ng * 16 + g * 4) = pk;
      }
      const bool full = (j0 + 63 <= iw0);
#pragma unroll
      for (int nf = 0; nf < 4; ++nf) {
        int c3 = il - (nf * 16 + g * 4 + 3) + 63;
        int base4 = c3 & ~3;
        int o = c3 & 3;
        const ushort_t* gp = gw + il * 84 + base4;
        uint64_t av = *reinterpret_cast<const uint64_t*>(gp);
        uint64_t bv2 = *reinterpret_cast<const uint64_t*>(gp + 4);
        uint64_t vv = o ? ((av >> (16 * o)) | (bv2 << (64 - 16 * o))) : av;
#pragma unroll
        for (int r = 0; r < 4; ++r) {
          int jl = nf * 16 + g * 4 + r;
          float sv = S[nf][r] + bf2f((ushort_t)(vv >> (16 * (3 - r))));
          if (!full) sv = (j0 + jl <= iw0 + il) ? sv : -1e30f;
          S[nf][r] = sv;
        }
      }
#pragma unroll
      for (int nf = 0; nf < 4; ++nf) {
        us4 pk;
#pragma unroll
        for (int r = 0; r < 4; ++r) {
          float p = fexp2(S[nf][r]);
          lsum += p;
          pk[r] = f2bt(p);
        }
        int off = (il * 128 + (nf * 16 + g * 4) * 2) ^ ((il & 7) << 4);
        *reinterpret_cast<us4*>(pw + off) = pk;
      }
      __builtin_amdgcn_s_setprio(1);
#pragma unroll
      for (int kf = 0; kf < 2; ++kf) {
        int poff = (il * 128 + (kf * 32 + lkb) * 2) ^ ((il & 7) << 4);
        bf16x8 pt = *reinterpret_cast<const bf16x8*>(pw + poff);
#pragma unroll
        for (int nf = 0; nf < 4; ++nf) {
          int r = nf * 16 + il;
          int voff = (r * 128 + (kf * 32 + lkb) * 2) ^ ((r & 7) << 4);
          Oa[nf] = mfma16(*reinterpret_cast<const bf16x8*>((char*)Vs + voff), pt, Oa[nf]);
        }
      }
      __builtin_amdgcn_s_setprio(0);
      __syncthreads();
      cur ^= 1;
    }
    lsum += __shfl_xor(lsum, 16, 64);
    lsum += __shfl_xor(lsum, 32, 64);
    float invl = 1.f / lsum;
    int ig = iw0 + il;
    int tout = dir ? (2047 - ig) : ig;
    size_t orow = ((size_t)tout * 2 + b) * 1024 + colbase + n * 64;
#pragma unroll
    for (int nf = 0; nf < 4; ++nf) {
      us4 pk;
#pragma unroll
      for (int r = 0; r < 4; ++r) pk[r] = f2bf(Oa[nf][r] * invl);
      *reinterpret_cast<us4*>(outp + orow + nf * 16 + g * 4) = pk;
    }
  }
}

// ------------------------------- host --------------------------------------
extern "C" void kernel_launch(void* const* d_in, const int* in_sizes, int n_in,
                              void* d_out, int out_size, void* d_ws, size_t ws_size,
                              hipStream_t stream) {
  (void)in_sizes; (void)n_in; (void)out_size; (void)ws_size;
  const float* x    = (const float*)d_in[0];
  const float* pos  = (const float*)d_in[1];
  const float* ln1g = (const float*)d_in[4];
  const float* ln1b = (const float*)d_in[5];
  const float* ln2g = (const float*)d_in[6];
  const float* ln2b = (const float*)d_in[7];
  const float* ln3g = (const float*)d_in[8];
  const float* ln3b = (const float*)d_in[9];
  const float* qkvf = (const float*)d_in[10];
  const float* rnetf= (const float*)d_in[11];
  const float* rwbf = (const float*)d_in[12];
  const float* rrbf = (const float*)d_in[13];
  const float* qkvb = (const float*)d_in[14];
  const float* rnetb= (const float*)d_in[15];
  const float* rwbb = (const float*)d_in[16];
  const float* rrbb = (const float*)d_in[17];
  const float* wo   = (const float*)d_in[18];
  const float* bo   = (const float*)d_in[19];
  const float* w1   = (const float*)d_in[20];
  const float* b1   = (const float*)d_in[21];
  const float* w2   = (const float*)d_in[22];
  const float* b2   = (const float*)d_in[23];
  float* out = (float*)d_out;
  char* ws = (char*)d_ws;
  auto U = [&](size_t off) { return (ushort_t*)(ws + off); };

  // prep: all weight conversions + dual LN in one launch
  PrepArgs pa;
  const float* srcs[8] = {qkvf, qkvb, rnetf, rnetb, wo, w1, w2, pos};
  size_t dsts[8] = {O_QKV_F, O_QKV_B, O_RNET_F, O_RNET_B, O_WO, O_W1, O_W2, O_POS};
  int bl[8] = {1536, 1536, 512, 512, 1024, 4096, 4096, 2048};
  int cum = 0;
  for (int s = 0; s < 8; ++s) {
    pa.src[s] = srcs[s];
    pa.dst[s] = U(dsts[s]);
    pa.bstart[s] = cum;
    cum += bl[s];
  }
  pa.cvt_blocks = cum;
  pa.x = x; pa.g1 = ln1g; pa.b1 = ln1b; pa.g2 = ln2g; pa.b2 = ln2b;
  pa.o1 = U(O_LN1); pa.o2 = U(O_LN2);
  prep_k<<<dim3(cum + 4096), dim3(256), 0, stream>>>(pa);

  // merged QKV (fused post) + rk (fused reverse): flat 896-block launch
  qkvrk_k<<<dim3(896), dim3(256), 0, stream>>>(
      U(O_LN1), U(O_LN2), U(O_POS),
      U(O_QKV_F), U(O_QKV_B), U(O_RNET_F), U(O_RNET_B),
      ws, rwbf, rrbf, rwbb, rrbb);

  v_trans2_k<<<dim3(32, 16, 2), dim3(256), 0, stream>>>(U(O_HEADS_F), U(O_HEADS_B), ws);

  attn_k<<<dim3(16, 16, 2), dim3(256), 0, stream>>>(ws, U(O_ACAT));

  gemm64<2><<<dim3(8, 64, 1), dim3(256), 0, stream>>>(
      U(O_ACAT), U(O_ACAT), U(O_WO), U(O_WO), ws + O_H, ws + O_H,
      bo, x, 4096, 1024, 1024);

  ln_one_k<<<dim3(4096), dim3(256), 0, stream>>>((const float*)(ws + O_H), ln3g, ln3b, U(O_LN3));
  gemm_bt<1><<<dim3(32, 32), dim3(256), 0, stream>>>(U(O_LN3), U(O_W1), U(O_FFNM), b1, nullptr, 4096, 4096, 1024);

  // ffn2: 128x128 split-K=2 (z = K-half), bf16 partials, then fused reduce
  ushort_t* part0 = U(O_FPART);
  ushort_t* part1 = U(O_FPART + 8388608);
  gemm_bt2<5><<<dim3(8, 32, 2), dim3(256), 0, stream>>>(
      U(O_FFNM), U(O_FFNM) + 2048, U(O_W2), U(O_W2) + 2048, part0, part1,
      4096, 1024, 2048, 4096, 4096);
  ffn2_red_k<<<dim3(4096), dim3(256), 0, stream>>>(
      part0, part1, b2, (const float*)(ws + O_H), out);
}